// Round 10
// baseline (416.429 us; speedup 1.0000x reference)
//
#include <hip/hip_runtime.h>
#include <hip/hip_bf16.h>
#include <math.h>

// Shapes: B=2, Le=250, Ld=150, N=400, Wl=16, Vin=128, E=64, F=128, K=5
//         H=8, hid=32, d=256, Vout=5000
// Inputs fp32, output fp32 (verified round 4). fixed_graph/dg_* dead:
// adj=clip(sigmoid+fixed,0,1) strictly positive => unmasked softmax.
// Round-9 lesson: per-kernel compute sums to ~30us; the other ~65us of the
// 101 is dispatch-boundary overhead (7 small kernels, ~5us each incl.
// ramp/drain). Fix: ONE persistent kernel (256 blocks x 1024 thr, 1
// block/CU co-resident by __launch_bounds__(1024,4)) with 6 device-scope
// ticket grid-barriers (counters memset to 0 per call; bounded spin
// failsafe). Phases use 4x 256-thread groups per block; all phase guards
// are block-uniform so __syncthreads is safe.

#define NBLK 256
#define NTHR 1024

__device__ __forceinline__ float bf2f_raw(unsigned int u) {
    union { unsigned int i; float f; } cv; cv.i = u << 16; return cv.f;
}
__device__ __forceinline__ unsigned short f2bf(float f) {
    __hip_bfloat16 h = __float2bfloat16(f);
    return *reinterpret_cast<unsigned short*>(&h);
}

struct AttnSm {                      // 10,224 B per group (16B-aligned)
    float4 plT[400];                 // p transposed: [m][4 rows]
    float f2l[400];
    float red[4][8][4][4];           // [wave][kq][rw][c]
    float sred[2][4][4];
    float f1l[8];
    float wmax[4];
};
union SM {
    struct { float er[4][64]; } tab;
    struct { int ids[4][16]; float xcl[4][128]; } ch;
    struct { float xr[4][2][256]; } wh;
    AttnSm at[4];
    struct { float xr[4][3][256]; } outp;
};

// device-scope grid barrier: one rep atomic per block, acquire-poll.
// ctr must be 0 at call start (memset'd); used once per call.
__device__ __forceinline__ void gridbar(unsigned int* ctr) {
    __syncthreads();                       // all block stores issued (vmcnt drained)
    if (threadIdx.x == 0) {
        __threadfence();                   // agent release: L2 writeback
        __hip_atomic_fetch_add(ctr, 1u, __ATOMIC_ACQ_REL, __HIP_MEMORY_SCOPE_AGENT);
        long spins = 0;
        while (__hip_atomic_load(ctr, __ATOMIC_ACQUIRE, __HIP_MEMORY_SCOPE_AGENT)
               < (unsigned int)NBLK) {
            __builtin_amdgcn_s_sleep(2);
            if (++spins > 3000000) break;  // failsafe: no infinite hang
        }
    }
    __syncthreads();
}

__global__ __launch_bounds__(NTHR, 4) void k_mega(
        const int* __restrict__ enc, const int* __restrict__ dec,
        const float* __restrict__ emb, const float* __restrict__ convw,
        const float* __restrict__ convb, const float* __restrict__ hstW,
        const float* __restrict__ hstb, const float* __restrict__ attW,
        const float* __restrict__ a1g, const float* __restrict__ a2g,
        const float* __restrict__ outW, const float* __restrict__ outb,
        float* T, float* xA, float* xB, float* Wh, float* f1, float* f2,
        unsigned short* Wb, unsigned int* ctr, float* out) {
    __shared__ SM sm;
    int bid = blockIdx.x, t = threadIdx.x;
    int grp = t >> 8, tt = t & 255;
    int slot = bid * 4 + grp;

    // ---- Phase 0: conv table T[k5][v][f] (blocks 0..31) + out_W -> bf16 (all)
    if (bid < 32) {
        int v = slot;
        if (tt < 64) sm.tab.er[grp][tt] = emb[v * 64 + tt];
        __syncthreads();
        if (tt < 128) {
            float acc[5] = {0.f, 0.f, 0.f, 0.f, 0.f};
            const float* w = convw + tt * 320;       // convw[f][e][k5]
            for (int e = 0; e < 64; ++e) {
                float xe = sm.tab.er[grp][e];
#pragma unroll
                for (int k = 0; k < 5; ++k) acc[k] += xe * w[e * 5 + k];
            }
#pragma unroll
            for (int k = 0; k < 5; ++k) T[(k * 128 + v) * 128 + tt] = acc[k];
        }
    }
    {
        int gid = bid * NTHR + t;                    // 640,000 bf16-pairs
        for (int p = gid; p < 640000; p += NBLK * NTHR) {
            float2 w2 = *reinterpret_cast<const float2*>(outW + 2 * p);
            unsigned int u = ((unsigned int)f2bf(w2.y) << 16) | f2bf(w2.x);
            reinterpret_cast<unsigned int*>(Wb)[p] = u;
        }
    }
    gridbar(ctr + 0);

    // ---- Phase 1: char conv + bias + relu + maxpool + hst proj (slots=words)
    if (bid < 200) {
        int w = slot, b = w / 400, n = w % 400;
        if (tt < 16)
            sm.ch.ids[grp][tt] = (n < 250) ? enc[(b * 250 + n) * 16 + tt]
                                           : dec[(b * 150 + (n - 250)) * 16 + tt];
        __syncthreads();
        if (tt < 128) {
            float best = -1e30f;
            for (int p = 0; p < 16; ++p) {
                float s = 0.f;
#pragma unroll
                for (int k = 0; k < 5; ++k) {
                    int q = p + k - 2;
                    if (q >= 0 && q < 16) s += T[(k * 128 + sm.ch.ids[grp][q]) * 128 + tt];
                }
                best = fmaxf(best, s);
            }
            sm.ch.xcl[grp][tt] = fmaxf(best + convb[tt], 0.f);
        }
        __syncthreads();
        float acc = hstb[tt];
        for (int c = 0; c < 128; ++c) acc += sm.ch.xcl[grp][c] * hstW[c * 256 + tt];
        xA[w * 256 + tt] = acc;
    }
    gridbar(ctr + 1);

    // ---- 2x { wh ; attn } ----
    float* xi = xA;
    float* xo = xB;
    for (int it = 0; it < 2; ++it) {
        // wh: Wh[bh][n][k] + fused f1/f2 (slots 0..399, 2 words each)
        if (bid < 100) {
            int w0 = slot * 2;
            int h = tt >> 5, k = tt & 31;
            for (int i = tt; i < 512; i += 256)
                sm.wh.xr[grp][i >> 8][i & 255] = xi[w0 * 256 + i];
            __syncthreads();
            float acc0 = 0.f, acc1 = 0.f;
            const float* Wp = attW + h * 8192 + k;
#pragma unroll 8
            for (int d = 0; d < 256; ++d) {
                float wv = Wp[d * 32];
                acc0 += sm.wh.xr[grp][0][d] * wv;
                acc1 += sm.wh.xr[grp][1][d] * wv;
            }
            float a1v = a1g[tt], a2v = a2g[tt];
            int bq = w0 / 400;
            int bh = bq * 8 + h;
            float accs[2] = {acc0, acc1};
#pragma unroll
            for (int rw = 0; rw < 2; ++rw) {
                int n = (w0 + rw) % 400;
                Wh[(bh * 400 + n) * 32 + k] = accs[rw];
                float v1 = accs[rw] * a1v, v2 = accs[rw] * a2v;
#pragma unroll
                for (int mm = 16; mm >= 1; mm >>= 1) {
                    v1 += __shfl_xor(v1, mm, 64);
                    v2 += __shfl_xor(v2, mm, 64);
                }
                if (k == 0) { f1[bh * 400 + n] = v1; f2[bh * 400 + n] = v2; }
            }
        }
        gridbar(ctr + 2 + it * 2);

        // attn: softmax (unmasked) + PV + elu (slots: bh=slot/50, tile=slot%50)
        if (bid < 200) {
            AttnSm& A = sm.at[grp];
            int bh = slot / 50, tile = slot % 50;
            int b = bh >> 3, h = bh & 7;
            int n0 = tile * 8;
            float fm = -1e30f;
            for (int m = tt; m < 400; m += 256) {
                float v = f2[bh * 400 + m];
                A.f2l[m] = v;
                fm = fmaxf(fm, v);
            }
            if (tt < 8) A.f1l[tt] = f1[bh * 400 + n0 + tt];
#pragma unroll
            for (int mm = 32; mm >= 1; mm >>= 1) fm = fmaxf(fm, __shfl_xor(fm, mm, 64));
            if ((tt & 63) == 0) A.wmax[tt >> 6] = fm;
            __syncthreads();
            float fmax2 = fmaxf(fmaxf(A.wmax[0], A.wmax[1]), fmaxf(A.wmax[2], A.wmax[3]));
            int g = tt & 7, kq = (tt >> 3) & 7, wv = tt >> 6;
            int gm = g + 8 * wv;
            const float4* WhG = (const float4*)(Wh + bh * 12800);
            for (int jt = 0; jt < 2; ++jt) {
                // P1: p for 4 rows at this thread's m -> plT[m]; denom partials
                float f1a = A.f1l[jt * 4 + 0], f1b = A.f1l[jt * 4 + 1];
                float f1c = A.f1l[jt * 4 + 2], f1d = A.f1l[jt * 4 + 3];
                float rm0 = f1a + fmax2; rm0 = rm0 > 0.f ? rm0 : 0.2f * rm0;
                float rm1 = f1b + fmax2; rm1 = rm1 > 0.f ? rm1 : 0.2f * rm1;
                float rm2 = f1c + fmax2; rm2 = rm2 > 0.f ? rm2 : 0.2f * rm2;
                float rm3 = f1d + fmax2; rm3 = rm3 > 0.f ? rm3 : 0.2f * rm3;
                float ps0 = 0.f, ps1 = 0.f, ps2 = 0.f, ps3 = 0.f;
                for (int m = tt; m < 400; m += 256) {
                    float f2v = A.f2l[m];
                    float e0 = f1a + f2v; e0 = e0 > 0.f ? e0 : 0.2f * e0;
                    float e1 = f1b + f2v; e1 = e1 > 0.f ? e1 : 0.2f * e1;
                    float e2 = f1c + f2v; e2 = e2 > 0.f ? e2 : 0.2f * e2;
                    float e3 = f1d + f2v; e3 = e3 > 0.f ? e3 : 0.2f * e3;
                    float4 pv;
                    pv.x = __expf(e0 - rm0); ps0 += pv.x;
                    pv.y = __expf(e1 - rm1); ps1 += pv.y;
                    pv.z = __expf(e2 - rm2); ps2 += pv.z;
                    pv.w = __expf(e3 - rm3); ps3 += pv.w;
                    A.plT[m] = pv;
                }
#pragma unroll
                for (int mm = 32; mm >= 1; mm >>= 1) {
                    ps0 += __shfl_xor(ps0, mm, 64);
                    ps1 += __shfl_xor(ps1, mm, 64);
                    ps2 += __shfl_xor(ps2, mm, 64);
                    ps3 += __shfl_xor(ps3, mm, 64);
                }
                if ((tt & 63) == 0) {
                    int wq = tt >> 6;
                    A.sred[jt & 1][0][wq] = ps0; A.sred[jt & 1][1][wq] = ps1;
                    A.sred[jt & 1][2][wq] = ps2; A.sred[jt & 1][3][wq] = ps3;
                }
                __syncthreads();
                // P2: 4 rows x 4 cols; 1 global b128 (Wh, L2) + 1 LDS b128 per m
                float a[4][4];
#pragma unroll
                for (int rr = 0; rr < 4; ++rr)
#pragma unroll
                    for (int c = 0; c < 4; ++c) a[rr][c] = 0.f;
                for (int m = gm; m < 400; m += 32) {
                    float4 w4 = WhG[m * 8 + kq];
                    float4 p4 = A.plT[m];
                    a[0][0] += p4.x * w4.x; a[0][1] += p4.x * w4.y; a[0][2] += p4.x * w4.z; a[0][3] += p4.x * w4.w;
                    a[1][0] += p4.y * w4.x; a[1][1] += p4.y * w4.y; a[1][2] += p4.y * w4.z; a[1][3] += p4.y * w4.w;
                    a[2][0] += p4.z * w4.x; a[2][1] += p4.z * w4.y; a[2][2] += p4.z * w4.z; a[2][3] += p4.z * w4.w;
                    a[3][0] += p4.w * w4.x; a[3][1] += p4.w * w4.y; a[3][2] += p4.w * w4.z; a[3][3] += p4.w * w4.w;
                }
#pragma unroll
                for (int rr = 0; rr < 4; ++rr)
#pragma unroll
                    for (int c = 0; c < 4; ++c) {
                        float v = a[rr][c];
                        v += __shfl_xor(v, 1, 64);   // DPP, off the LDS pipe
                        v += __shfl_xor(v, 2, 64);
                        v += __shfl_xor(v, 4, 64);
                        a[rr][c] = v;
                    }
                if (g == 0) {
#pragma unroll
                    for (int rr = 0; rr < 4; ++rr)
#pragma unroll
                        for (int c = 0; c < 4; ++c) A.red[wv][kq][rr][c] = a[rr][c];
                }
                __syncthreads();
                // P3: combine wave partials, normalize, elu, store
                if (tt < 128) {
                    int rw3 = tt >> 5, kk = tt & 31;
                    int q3 = kk >> 2, c3 = kk & 3;
                    float s = A.sred[jt & 1][rw3][0] + A.sred[jt & 1][rw3][1]
                            + A.sred[jt & 1][rw3][2] + A.sred[jt & 1][rw3][3];
                    float o = (A.red[0][q3][rw3][c3] + A.red[1][q3][rw3][c3]
                             + A.red[2][q3][rw3][c3] + A.red[3][q3][rw3][c3]) / s;
                    o = o > 0.f ? o : (__expf(o) - 1.f);   // elu
                    int n = n0 + jt * 4 + rw3;
                    xo[(b * 400 + n) * 256 + h * 32 + kk] = o;
                }
            }
        }
        gridbar(ctr + 3 + it * 2);
        float* tmp = xi; xi = xo; xo = tmp;
    }

    // ---- Phase out: out[r][v] = sum_d x[b,250+dn,d]*Wb[d][v] + b[v]
    if (bid < 250) {                                 // slots 0..999: vt, rg
        int vt = slot / 100, rg = slot % 100;
        int r0 = rg * 3;                             // 150%3==0: never crosses b
        int b = r0 / 150, n0 = 250 + (r0 % 150);
        for (int i = tt; i < 768; i += 256) {
            int rr = i >> 8, dd = i & 255;
            sm.outp.xr[grp][rr][dd] = xi[(b * 400 + n0 + rr) * 256 + dd];
        }
        __syncthreads();
        int v = vt * 512 + tt * 2;
        if (v < 5000) {
            float acc[3][2];
#pragma unroll
            for (int rr = 0; rr < 3; ++rr) { acc[rr][0] = 0.f; acc[rr][1] = 0.f; }
            const unsigned short* Wp = Wb + v;
#pragma unroll 8
            for (int dd = 0; dd < 256; ++dd) {
                unsigned int wu = *reinterpret_cast<const unsigned int*>(Wp + dd * 5000);
                float w0 = bf2f_raw(wu & 0xFFFFu);
                float w1 = bf2f_raw(wu >> 16);
#pragma unroll
                for (int rr = 0; rr < 3; ++rr) {
                    float xv = sm.outp.xr[grp][rr][dd];
                    acc[rr][0] += xv * w0;
                    acc[rr][1] += xv * w1;
                }
            }
            float b0 = outb[v], b1 = outb[v + 1];
#pragma unroll
            for (int rr = 0; rr < 3; ++rr) {
                out[(r0 + rr) * 5000 + v]     = acc[rr][0] + b0;
                out[(r0 + rr) * 5000 + v + 1] = acc[rr][1] + b1;
            }
        }
    }
}

extern "C" void kernel_launch(void* const* d_in, const int* in_sizes, int n_in,
                              void* d_out, int out_size, void* d_ws, size_t ws_size,
                              hipStream_t stream) {
    const int*   enc   = (const int*)d_in[0];
    const int*   dec   = (const int*)d_in[1];
    const float* emb   = (const float*)d_in[3];
    const float* convw = (const float*)d_in[4];
    const float* convb = (const float*)d_in[5];
    const float* hstW  = (const float*)d_in[6];
    const float* hstb  = (const float*)d_in[7];
    const float* attW  = (const float*)d_in[15];
    const float* a1    = (const float*)d_in[16];
    const float* a2    = (const float*)d_in[17];
    const float* outW  = (const float*)d_in[18];
    const float* outb  = (const float*)d_in[19];
    float* out = (float*)d_out;

    char* ws = (char*)d_ws;
    unsigned int* ctr = (unsigned int*)ws; ws += 256;
    float* T   = (float*)ws; ws += 5 * 128 * 128 * 4;
    float* xA  = (float*)ws; ws += 800 * 256 * 4;
    float* xB  = (float*)ws; ws += 800 * 256 * 4;
    float* Wh  = (float*)ws; ws += 16 * 400 * 32 * 4;
    float* f1  = (float*)ws; ws += 16 * 400 * 4;
    float* f2  = (float*)ws; ws += 16 * 400 * 4;
    unsigned short* Wb = (unsigned short*)ws; ws += 256 * 5000 * 2;

    hipMemsetAsync(ctr, 0, 256, stream);             // zero barrier counters
    k_mega<<<NBLK, NTHR, 0, stream>>>(enc, dec, emb, convw, convb, hstW, hstb,
                                      attW, a1, a2, outW, outb,
                                      T, xA, xB, Wh, f1, f2, Wb, ctr, out);
}

// Round 11
// 242.536 us; speedup vs baseline: 1.7170x; 1.7170x over previous
//
#include <hip/hip_runtime.h>
#include <hip/hip_bf16.h>
#include <math.h>

// Shapes: B=2, Le=250, Ld=150, N=400, Wl=16, Vin=128, E=64, F=128, K=5
//         H=8, hid=32, d=256, Vout=5000
// Inputs fp32, output fp32 (verified round 4). fixed_graph/dg_* dead:
// adj=clip(sigmoid+fixed,0,1) strictly positive => unmasked softmax.
// Round-10 post-mortem: 416us because the grid-barrier spin used ACQUIRE
// polls -> buffer_inv (whole-XCD L2 invalidate) every ~128cy from every
// waiting block, thrashing the L2 of still-computing blocks (FETCH 7->24MB,
// VALUBusy 6.5%). Fix: fence-based barrier -- release = syncthreads +
// ONE __threadfence + RELAXED add; spin = RELAXED agent loads (sc1, bypass
// non-coherent L2, no cache maintenance); acquire = ONE __threadfence after
// the spin. 2 cache-maintenance ops per block per barrier instead of ~1000s.

#define NBLK 256
#define NTHR 1024

__device__ __forceinline__ float bf2f_raw(unsigned int u) {
    union { unsigned int i; float f; } cv; cv.i = u << 16; return cv.f;
}
__device__ __forceinline__ unsigned short f2bf(float f) {
    __hip_bfloat16 h = __float2bfloat16(f);
    return *reinterpret_cast<unsigned short*>(&h);
}

struct AttnSm {                      // 10,224 B per group (16B-aligned)
    float4 plT[400];                 // p transposed: [m][4 rows]
    float f2l[400];
    float red[4][8][4][4];           // [wave][kq][rw][c]
    float sred[2][4][4];
    float f1l[8];
    float wmax[4];
};
union SM {
    struct { float er[4][64]; } tab;
    struct { int ids[4][16]; float xcl[4][128]; } ch;
    struct { float xr[4][2][256]; } wh;
    AttnSm at[4];
    struct { float xr[4][3][256]; } outp;
};

// Fence-based grid barrier. ctr (64B-padded) must be 0 at call start.
// Release: one threadfence (wb) + RELAXED add. Spin: RELAXED agent loads
// (coherent-point reads, NO per-poll invalidate). Acquire: one threadfence.
__device__ __forceinline__ void gridbar(unsigned int* ctr) {
    __syncthreads();                       // block stores drained (vmcnt)
    if (threadIdx.x == 0) {
        __threadfence();                   // writeback this XCD's L2
        __hip_atomic_fetch_add(ctr, 1u, __ATOMIC_RELAXED, __HIP_MEMORY_SCOPE_AGENT);
        long spins = 0;
        while (__hip_atomic_load(ctr, __ATOMIC_RELAXED, __HIP_MEMORY_SCOPE_AGENT)
               < (unsigned int)NBLK) {
            __builtin_amdgcn_s_sleep(2);
            if (++spins > 200000) break;   // failsafe: bounded, never expected
        }
        __threadfence();                   // invalidate L1 + this XCD's L2
    }
    __syncthreads();
}

__global__ __launch_bounds__(NTHR, 4) void k_mega(
        const int* __restrict__ enc, const int* __restrict__ dec,
        const float* __restrict__ emb, const float* __restrict__ convw,
        const float* __restrict__ convb, const float* __restrict__ hstW,
        const float* __restrict__ hstb, const float* __restrict__ attW,
        const float* __restrict__ a1g, const float* __restrict__ a2g,
        const float* __restrict__ outW, const float* __restrict__ outb,
        float* T, float* xA, float* xB, float* Wh, float* f1, float* f2,
        unsigned short* Wb, unsigned int* ctr, float* out) {
    __shared__ SM sm;
    int bid = blockIdx.x, t = threadIdx.x;
    int grp = t >> 8, tt = t & 255;
    int slot = bid * 4 + grp;

    // ---- Phase 0: conv table T[k5][v][f] (blocks 0..31) + out_W -> bf16 (all)
    if (bid < 32) {
        int v = slot;
        if (tt < 64) sm.tab.er[grp][tt] = emb[v * 64 + tt];
        __syncthreads();
        if (tt < 128) {
            float acc[5] = {0.f, 0.f, 0.f, 0.f, 0.f};
            const float* w = convw + tt * 320;       // convw[f][e][k5]
            for (int e = 0; e < 64; ++e) {
                float xe = sm.tab.er[grp][e];
#pragma unroll
                for (int k = 0; k < 5; ++k) acc[k] += xe * w[e * 5 + k];
            }
#pragma unroll
            for (int k = 0; k < 5; ++k) T[(k * 128 + v) * 128 + tt] = acc[k];
        }
    }
    {
        int gid = bid * NTHR + t;                    // 640,000 bf16-pairs
        for (int p = gid; p < 640000; p += NBLK * NTHR) {
            float2 w2 = *reinterpret_cast<const float2*>(outW + 2 * p);
            unsigned int u = ((unsigned int)f2bf(w2.y) << 16) | f2bf(w2.x);
            reinterpret_cast<unsigned int*>(Wb)[p] = u;
        }
    }
    gridbar(ctr + 0 * 16);

    // ---- Phase 1: char conv + bias + relu + maxpool + hst proj (slots=words)
    if (bid < 200) {
        int w = slot, b = w / 400, n = w % 400;
        if (tt < 16)
            sm.ch.ids[grp][tt] = (n < 250) ? enc[(b * 250 + n) * 16 + tt]
                                           : dec[(b * 150 + (n - 250)) * 16 + tt];
        __syncthreads();
        if (tt < 128) {
            float best = -1e30f;
            for (int p = 0; p < 16; ++p) {
                float s = 0.f;
#pragma unroll
                for (int k = 0; k < 5; ++k) {
                    int q = p + k - 2;
                    if (q >= 0 && q < 16) s += T[(k * 128 + sm.ch.ids[grp][q]) * 128 + tt];
                }
                best = fmaxf(best, s);
            }
            sm.ch.xcl[grp][tt] = fmaxf(best + convb[tt], 0.f);
        }
        __syncthreads();
        float acc = hstb[tt];
        for (int c = 0; c < 128; ++c) acc += sm.ch.xcl[grp][c] * hstW[c * 256 + tt];
        xA[w * 256 + tt] = acc;
    }
    gridbar(ctr + 1 * 16);

    // ---- 2x { wh ; attn } ----
    float* xi = xA;
    float* xo = xB;
    for (int it = 0; it < 2; ++it) {
        // wh: Wh[bh][n][k] + fused f1/f2 (slots 0..399, 2 words each)
        if (bid < 100) {
            int w0 = slot * 2;
            int h = tt >> 5, k = tt & 31;
            for (int i = tt; i < 512; i += 256)
                sm.wh.xr[grp][i >> 8][i & 255] = xi[w0 * 256 + i];
            __syncthreads();
            float acc0 = 0.f, acc1 = 0.f;
            const float* Wp = attW + h * 8192 + k;
#pragma unroll 8
            for (int d = 0; d < 256; ++d) {
                float wv = Wp[d * 32];
                acc0 += sm.wh.xr[grp][0][d] * wv;
                acc1 += sm.wh.xr[grp][1][d] * wv;
            }
            float a1v = a1g[tt], a2v = a2g[tt];
            int bq = w0 / 400;
            int bh = bq * 8 + h;
            float accs[2] = {acc0, acc1};
#pragma unroll
            for (int rw = 0; rw < 2; ++rw) {
                int n = (w0 + rw) % 400;
                Wh[(bh * 400 + n) * 32 + k] = accs[rw];
                float v1 = accs[rw] * a1v, v2 = accs[rw] * a2v;
#pragma unroll
                for (int mm = 16; mm >= 1; mm >>= 1) {
                    v1 += __shfl_xor(v1, mm, 64);
                    v2 += __shfl_xor(v2, mm, 64);
                }
                if (k == 0) { f1[bh * 400 + n] = v1; f2[bh * 400 + n] = v2; }
            }
        }
        gridbar(ctr + (2 + it * 2) * 16);

        // attn: softmax (unmasked) + PV + elu (slots: bh=slot/50, tile=slot%50)
        if (bid < 200) {
            AttnSm& A = sm.at[grp];
            int bh = slot / 50, tile = slot % 50;
            int b = bh >> 3, h = bh & 7;
            int n0 = tile * 8;
            float fm = -1e30f;
            for (int m = tt; m < 400; m += 256) {
                float v = f2[bh * 400 + m];
                A.f2l[m] = v;
                fm = fmaxf(fm, v);
            }
            if (tt < 8) A.f1l[tt] = f1[bh * 400 + n0 + tt];
#pragma unroll
            for (int mm = 32; mm >= 1; mm >>= 1) fm = fmaxf(fm, __shfl_xor(fm, mm, 64));
            if ((tt & 63) == 0) A.wmax[tt >> 6] = fm;
            __syncthreads();
            float fmax2 = fmaxf(fmaxf(A.wmax[0], A.wmax[1]), fmaxf(A.wmax[2], A.wmax[3]));
            int g = tt & 7, kq = (tt >> 3) & 7, wv = tt >> 6;
            int gm = g + 8 * wv;
            const float4* WhG = (const float4*)(Wh + bh * 12800);
            for (int jt = 0; jt < 2; ++jt) {
                // P1: p for 4 rows at this thread's m -> plT[m]; denom partials
                float f1a = A.f1l[jt * 4 + 0], f1b = A.f1l[jt * 4 + 1];
                float f1c = A.f1l[jt * 4 + 2], f1d = A.f1l[jt * 4 + 3];
                float rm0 = f1a + fmax2; rm0 = rm0 > 0.f ? rm0 : 0.2f * rm0;
                float rm1 = f1b + fmax2; rm1 = rm1 > 0.f ? rm1 : 0.2f * rm1;
                float rm2 = f1c + fmax2; rm2 = rm2 > 0.f ? rm2 : 0.2f * rm2;
                float rm3 = f1d + fmax2; rm3 = rm3 > 0.f ? rm3 : 0.2f * rm3;
                float ps0 = 0.f, ps1 = 0.f, ps2 = 0.f, ps3 = 0.f;
                for (int m = tt; m < 400; m += 256) {
                    float f2v = A.f2l[m];
                    float e0 = f1a + f2v; e0 = e0 > 0.f ? e0 : 0.2f * e0;
                    float e1 = f1b + f2v; e1 = e1 > 0.f ? e1 : 0.2f * e1;
                    float e2 = f1c + f2v; e2 = e2 > 0.f ? e2 : 0.2f * e2;
                    float e3 = f1d + f2v; e3 = e3 > 0.f ? e3 : 0.2f * e3;
                    float4 pv;
                    pv.x = __expf(e0 - rm0); ps0 += pv.x;
                    pv.y = __expf(e1 - rm1); ps1 += pv.y;
                    pv.z = __expf(e2 - rm2); ps2 += pv.z;
                    pv.w = __expf(e3 - rm3); ps3 += pv.w;
                    A.plT[m] = pv;
                }
#pragma unroll
                for (int mm = 32; mm >= 1; mm >>= 1) {
                    ps0 += __shfl_xor(ps0, mm, 64);
                    ps1 += __shfl_xor(ps1, mm, 64);
                    ps2 += __shfl_xor(ps2, mm, 64);
                    ps3 += __shfl_xor(ps3, mm, 64);
                }
                if ((tt & 63) == 0) {
                    int wq = tt >> 6;
                    A.sred[jt & 1][0][wq] = ps0; A.sred[jt & 1][1][wq] = ps1;
                    A.sred[jt & 1][2][wq] = ps2; A.sred[jt & 1][3][wq] = ps3;
                }
                __syncthreads();
                // P2: 4 rows x 4 cols; 1 global b128 (Wh, L2) + 1 LDS b128 per m
                float a[4][4];
#pragma unroll
                for (int rr = 0; rr < 4; ++rr)
#pragma unroll
                    for (int c = 0; c < 4; ++c) a[rr][c] = 0.f;
                for (int m = gm; m < 400; m += 32) {
                    float4 w4 = WhG[m * 8 + kq];
                    float4 p4 = A.plT[m];
                    a[0][0] += p4.x * w4.x; a[0][1] += p4.x * w4.y; a[0][2] += p4.x * w4.z; a[0][3] += p4.x * w4.w;
                    a[1][0] += p4.y * w4.x; a[1][1] += p4.y * w4.y; a[1][2] += p4.y * w4.z; a[1][3] += p4.y * w4.w;
                    a[2][0] += p4.z * w4.x; a[2][1] += p4.z * w4.y; a[2][2] += p4.z * w4.z; a[2][3] += p4.z * w4.w;
                    a[3][0] += p4.w * w4.x; a[3][1] += p4.w * w4.y; a[3][2] += p4.w * w4.z; a[3][3] += p4.w * w4.w;
                }
#pragma unroll
                for (int rr = 0; rr < 4; ++rr)
#pragma unroll
                    for (int c = 0; c < 4; ++c) {
                        float v = a[rr][c];
                        v += __shfl_xor(v, 1, 64);   // DPP, off the LDS pipe
                        v += __shfl_xor(v, 2, 64);
                        v += __shfl_xor(v, 4, 64);
                        a[rr][c] = v;
                    }
                if (g == 0) {
#pragma unroll
                    for (int rr = 0; rr < 4; ++rr)
#pragma unroll
                        for (int c = 0; c < 4; ++c) A.red[wv][kq][rr][c] = a[rr][c];
                }
                __syncthreads();
                // P3: combine wave partials, normalize, elu, store
                if (tt < 128) {
                    int rw3 = tt >> 5, kk = tt & 31;
                    int q3 = kk >> 2, c3 = kk & 3;
                    float s = A.sred[jt & 1][rw3][0] + A.sred[jt & 1][rw3][1]
                            + A.sred[jt & 1][rw3][2] + A.sred[jt & 1][rw3][3];
                    float o = (A.red[0][q3][rw3][c3] + A.red[1][q3][rw3][c3]
                             + A.red[2][q3][rw3][c3] + A.red[3][q3][rw3][c3]) / s;
                    o = o > 0.f ? o : (__expf(o) - 1.f);   // elu
                    int n = n0 + jt * 4 + rw3;
                    xo[(b * 400 + n) * 256 + h * 32 + kk] = o;
                }
            }
        }
        gridbar(ctr + (3 + it * 2) * 16);
        float* tmp = xi; xi = xo; xo = tmp;
    }

    // ---- Phase out: out[r][v] = sum_d x[b,250+dn,d]*Wb[d][v] + b[v]
    if (bid < 250) {                                 // slots 0..999: vt, rg
        int vt = slot / 100, rg = slot % 100;
        int r0 = rg * 3;                             // 150%3==0: never crosses b
        int b = r0 / 150, n0 = 250 + (r0 % 150);
        for (int i = tt; i < 768; i += 256) {
            int rr = i >> 8, dd = i & 255;
            sm.outp.xr[grp][rr][dd] = xi[(b * 400 + n0 + rr) * 256 + dd];
        }
        __syncthreads();
        int v = vt * 512 + tt * 2;
        if (v < 5000) {
            float acc[3][2];
#pragma unroll
            for (int rr = 0; rr < 3; ++rr) { acc[rr][0] = 0.f; acc[rr][1] = 0.f; }
            const unsigned short* Wp = Wb + v;
#pragma unroll 8
            for (int dd = 0; dd < 256; ++dd) {
                unsigned int wu = *reinterpret_cast<const unsigned int*>(Wp + dd * 5000);
                float w0 = bf2f_raw(wu & 0xFFFFu);
                float w1 = bf2f_raw(wu >> 16);
#pragma unroll
                for (int rr = 0; rr < 3; ++rr) {
                    float xv = sm.outp.xr[grp][rr][dd];
                    acc[rr][0] += xv * w0;
                    acc[rr][1] += xv * w1;
                }
            }
            float b0 = outb[v], b1 = outb[v + 1];
#pragma unroll
            for (int rr = 0; rr < 3; ++rr) {
                out[(r0 + rr) * 5000 + v]     = acc[rr][0] + b0;
                out[(r0 + rr) * 5000 + v + 1] = acc[rr][1] + b1;
            }
        }
    }
}

extern "C" void kernel_launch(void* const* d_in, const int* in_sizes, int n_in,
                              void* d_out, int out_size, void* d_ws, size_t ws_size,
                              hipStream_t stream) {
    const int*   enc   = (const int*)d_in[0];
    const int*   dec   = (const int*)d_in[1];
    const float* emb   = (const float*)d_in[3];
    const float* convw = (const float*)d_in[4];
    const float* convb = (const float*)d_in[5];
    const float* hstW  = (const float*)d_in[6];
    const float* hstb  = (const float*)d_in[7];
    const float* attW  = (const float*)d_in[15];
    const float* a1    = (const float*)d_in[16];
    const float* a2    = (const float*)d_in[17];
    const float* outW  = (const float*)d_in[18];
    const float* outb  = (const float*)d_in[19];
    float* out = (float*)d_out;

    char* ws = (char*)d_ws;
    unsigned int* ctr = (unsigned int*)ws; ws += 512;   // 6 ctrs, 64B apart
    float* T   = (float*)ws; ws += 5 * 128 * 128 * 4;
    float* xA  = (float*)ws; ws += 800 * 256 * 4;
    float* xB  = (float*)ws; ws += 800 * 256 * 4;
    float* Wh  = (float*)ws; ws += 16 * 400 * 32 * 4;
    float* f1  = (float*)ws; ws += 16 * 400 * 4;
    float* f2  = (float*)ws; ws += 16 * 400 * 4;
    unsigned short* Wb = (unsigned short*)ws; ws += 256 * 5000 * 2;

    hipMemsetAsync(ctr, 0, 512, stream);             // zero barrier counters
    k_mega<<<NBLK, NTHR, 0, stream>>>(enc, dec, emb, convw, convb, hstW, hstb,
                                      attW, a1, a2, outW, outb,
                                      T, xA, xB, Wh, f1, f2, Wb, ctr, out);
}

// Round 12
// 136.845 us; speedup vs baseline: 3.0431x; 1.7723x over previous
//
#include <hip/hip_runtime.h>
#include <hip/hip_bf16.h>
#include <math.h>

// Shapes: B=2, Le=250, Ld=150, N=400, Wl=16, Vin=128, E=64, F=128, K=5
//         H=8, hid=32, d=256, Vout=5000
// Inputs fp32, output fp32 (verified round 4). fixed_graph/dg_* dead:
// adj=clip(sigmoid+fixed,0,1) strictly positive => unmasked softmax.
// Round-10/11 lesson: software grid-sync on multi-XCD CDNA4 forces whole-L2
// wb+inv fences per barrier -> cold L2 every phase (FETCH 24MB, 242us).
// Reverted to multi-kernel (HW coherence at boundaries), restructured 7->5:
//   S1 prep: conv table T + out_W->bf16
//   S2 conv+hst+Wh1 fused (x row-local, LDS only; no global x)
//   S3 attn1(full rows, all heads; per-head reduction inside one wave)+Wh2
//   S4 attn2 for DECODER rows only (enc rows of final x are dead)
//   S5 out
// x never exists globally; attn2 is 62.5% smaller; 5 dispatches.

__device__ __forceinline__ float bf2f_raw(unsigned int u) {
    union { unsigned int i; float f; } cv; cv.i = u << 16; return cv.f;
}
__device__ __forceinline__ unsigned short f2bf(float f) {
    __hip_bfloat16 h = __float2bfloat16(f);
    return *reinterpret_cast<unsigned short*>(&h);
}
__device__ __forceinline__ float leaky(float e) { return e > 0.f ? e : 0.2f * e; }

// ---------- S1: conv table T[k5][v][f] (blocks 0..127) + out_W->bf16 (rest)
__global__ __launch_bounds__(256) void k_prep(const float* emb, const float* convw,
                                              float* T, const float* W,
                                              unsigned short* Wb) {
    int bid = blockIdx.x, t = threadIdx.x;
    if (bid < 128) {
        int v = bid;
        __shared__ float er[64];
        if (t < 64) er[t] = emb[v * 64 + t];
        __syncthreads();
        if (t < 128) {
            float acc[5] = {0.f, 0.f, 0.f, 0.f, 0.f};
            const float* w = convw + t * 320;          // convw[f][e][k5]
            for (int e = 0; e < 64; ++e) {
                float xe = er[e];
#pragma unroll
                for (int k = 0; k < 5; ++k) acc[k] += xe * w[e * 5 + k];
            }
#pragma unroll
            for (int k = 0; k < 5; ++k) T[(k * 128 + v) * 128 + t] = acc[k];
        }
    } else {
        int i0 = (bid - 128) * 512 + t * 2;            // 2500 blocks * 512
        if (i0 < 256 * 5000) {
            float2 w2 = *reinterpret_cast<const float2*>(W + i0);
            unsigned int u = ((unsigned int)f2bf(w2.y) << 16) | f2bf(w2.x);
            *reinterpret_cast<unsigned int*>(Wb + i0) = u;
        }
    }
}

// ---------- S2: char conv + bias + relu + maxpool + hst + Wh1 + f1/f2.
// 2 words/block; x rows live only in LDS.
__global__ __launch_bounds__(256) void k_convwh(const int* enc, const int* dec,
                                                const float* convb, const float* T,
                                                const float* hstW, const float* hstb,
                                                const float* attW,
                                                const float* a1g, const float* a2g,
                                                float* Wh, float* f1, float* f2) {
    int w0 = blockIdx.x * 2, t = threadIdx.x;          // grid 400
    __shared__ int ids[2][16];
    __shared__ float xcl[2][128];
    __shared__ float x0[2][256];
    if (t < 32) {
        int r = t >> 4, c = t & 15;
        int w = w0 + r, b = w / 400, n = w % 400;
        ids[r][c] = (n < 250) ? enc[(b * 250 + n) * 16 + c]
                              : dec[(b * 150 + (n - 250)) * 16 + c];
    }
    __syncthreads();
    {
        int r = t >> 7, f = t & 127;                   // conv: all 256 active
        float best = -1e30f;
        for (int p = 0; p < 16; ++p) {
            float s = 0.f;
#pragma unroll
            for (int k = 0; k < 5; ++k) {
                int q = p + k - 2;
                if (q >= 0 && q < 16) s += T[(k * 128 + ids[r][q]) * 128 + f];
            }
            best = fmaxf(best, s);
        }
        xcl[r][f] = fmaxf(best + convb[f], 0.f);
    }
    __syncthreads();
    {
        float acc0 = hstb[t], acc1 = acc0;             // hst: 2 rows share loads
        for (int c = 0; c < 128; ++c) {
            float wv = hstW[c * 256 + t];
            acc0 += xcl[0][c] * wv;
            acc1 += xcl[1][c] * wv;
        }
        x0[0][t] = acc0;
        x0[1][t] = acc1;
    }
    __syncthreads();
    // Wh1: thread (h,k)
    int h = t >> 5, k = t & 31;
    float acc0 = 0.f, acc1 = 0.f;
    const float* Wp = attW + h * 8192 + k;
#pragma unroll 8
    for (int d = 0; d < 256; ++d) {
        float wv = Wp[d * 32];
        acc0 += x0[0][d] * wv;
        acc1 += x0[1][d] * wv;
    }
    float a1v = a1g[t], a2v = a2g[t];
    int b = w0 / 400;
    int bh = b * 8 + h;
    float accs[2] = {acc0, acc1};
#pragma unroll
    for (int rw = 0; rw < 2; ++rw) {
        int n = (w0 + rw) % 400;
        Wh[(bh * 400 + n) * 32 + k] = accs[rw];
        float v1 = accs[rw] * a1v, v2 = accs[rw] * a2v;
#pragma unroll
        for (int mm = 16; mm >= 1; mm >>= 1) {
            v1 += __shfl_xor(v1, mm, 64);
            v2 += __shfl_xor(v2, mm, 64);
        }
        if (k == 0) { f1[bh * 400 + n] = v1; f2[bh * 400 + n] = v2; }
    }
}

// ---------- S3: attn1 (2 full rows, ALL 8 heads) + Wh2 + f1'/f2'.
// Per wave: 2 heads; lanes (g=t&7) partition m, (kq) partition cols; the
// whole per-head softmax+PV reduction stays inside the wave (DPP xor 1/2/4).
__global__ __launch_bounds__(256) void k_attnwh(const float* WhI, const float* f1I,
                                                const float* f2I, const float* attW,
                                                const float* a1g, const float* a2g,
                                                float* WhO, float* f1O, float* f2O) {
    int w0 = blockIdx.x * 2, t = threadIdx.x;          // grid 400
    int b = w0 / 400, n0 = w0 % 400;
    __shared__ float f2l[8][400];                      // 12.8 KB
    __shared__ float x1[2][256];
    __shared__ float f1l[8][2];
    __shared__ float fmax2[8];
    for (int h = 0; h < 8; ++h)
        for (int m = t; m < 400; m += 256)
            f2l[h][m] = f2I[(b * 8 + h) * 400 + m];
    if (t < 16) f1l[t >> 1][t & 1] = f1I[(b * 8 + (t >> 1)) * 400 + n0 + (t & 1)];
    __syncthreads();
    int wv = t >> 6, lane = t & 63;
    {   // per-head max of f2: wave wv covers h = 2wv + (lane>>5)
        int h = wv * 2 + (lane >> 5), mm0 = lane & 31;
        float fm = -1e30f;
        for (int m = mm0; m < 400; m += 32) fm = fmaxf(fm, f2l[h][m]);
#pragma unroll
        for (int s = 16; s >= 1; s >>= 1) fm = fmaxf(fm, __shfl_xor(fm, s, 64));
        if (mm0 == 0) fmax2[h] = fm;
    }
    __syncthreads();
    int g = t & 7, kq = (t >> 3) & 7;
    for (int hh = 0; hh < 2; ++hh) {                   // PV: 2 heads per wave
        int h = wv * 2 + hh;
        int bh = b * 8 + h;
        float f1a = f1l[h][0], f1b = f1l[h][1];
        float rm0 = leaky(f1a + fmax2[h]);
        float rm1 = leaky(f1b + fmax2[h]);
        float a0[4] = {0.f, 0.f, 0.f, 0.f}, a1r[4] = {0.f, 0.f, 0.f, 0.f};
        float ps0 = 0.f, ps1 = 0.f;
        const float4* WhG = (const float4*)(WhI + bh * 12800);
        for (int m = g; m < 400; m += 8) {
            float4 w4 = WhG[m * 8 + kq];
            float f2v = f2l[h][m];
            float p0 = __expf(leaky(f1a + f2v) - rm0); ps0 += p0;
            float p1 = __expf(leaky(f1b + f2v) - rm1); ps1 += p1;
            a0[0] += p0 * w4.x; a0[1] += p0 * w4.y; a0[2] += p0 * w4.z; a0[3] += p0 * w4.w;
            a1r[0] += p1 * w4.x; a1r[1] += p1 * w4.y; a1r[2] += p1 * w4.z; a1r[3] += p1 * w4.w;
        }
#pragma unroll
        for (int s = 4; s >= 1; s >>= 1) {             // reduce over g (DPP)
            ps0 += __shfl_xor(ps0, s, 64);
            ps1 += __shfl_xor(ps1, s, 64);
#pragma unroll
            for (int c = 0; c < 4; ++c) {
                a0[c] += __shfl_xor(a0[c], s, 64);
                a1r[c] += __shfl_xor(a1r[c], s, 64);
            }
        }
        if (g == 0) {
            float4 o0, o1;
            float* p0v = &o0.x; float* p1v = &o1.x;
#pragma unroll
            for (int c = 0; c < 4; ++c) {
                float v0 = a0[c] / ps0; p0v[c] = v0 > 0.f ? v0 : (__expf(v0) - 1.f);
                float v1 = a1r[c] / ps1; p1v[c] = v1 > 0.f ? v1 : (__expf(v1) - 1.f);
            }
            *(float4*)&x1[0][h * 32 + kq * 4] = o0;
            *(float4*)&x1[1][h * 32 + kq * 4] = o1;
        }
    }
    __syncthreads();
    // Wh2 from in-LDS x1 (same shape as S2's wh)
    int h = t >> 5, k = t & 31;
    float acc0 = 0.f, acc1 = 0.f;
    const float* Wp = attW + h * 8192 + k;
#pragma unroll 8
    for (int d = 0; d < 256; ++d) {
        float wv2 = Wp[d * 32];
        acc0 += x1[0][d] * wv2;
        acc1 += x1[1][d] * wv2;
    }
    float a1v = a1g[t], a2v = a2g[t];
    int bh = b * 8 + h;
    float accs[2] = {acc0, acc1};
#pragma unroll
    for (int rw = 0; rw < 2; ++rw) {
        int n = n0 + rw;
        WhO[(bh * 400 + n) * 32 + k] = accs[rw];
        float v1 = accs[rw] * a1v, v2 = accs[rw] * a2v;
#pragma unroll
        for (int mm = 16; mm >= 1; mm >>= 1) {
            v1 += __shfl_xor(v1, mm, 64);
            v2 += __shfl_xor(v2, mm, 64);
        }
        if (k == 0) { f1O[bh * 400 + n] = v1; f2O[bh * 400 + n] = v2; }
    }
}

// ---------- S4: attn2 for decoder rows only (n >= 250); writes x rows.
__global__ __launch_bounds__(256) void k_attn2(const float* WhI, const float* f1I,
                                               const float* f2I, float* xout) {
    int bid = blockIdx.x, t = threadIdx.x;             // grid 300
    int b = bid / 150, n = 250 + (bid % 150);
    __shared__ float f2l[8][400];
    __shared__ float f1l[8];
    __shared__ float fmax2[8];
    for (int h = 0; h < 8; ++h)
        for (int m = t; m < 400; m += 256)
            f2l[h][m] = f2I[(b * 8 + h) * 400 + m];
    if (t < 8) f1l[t] = f1I[(b * 8 + t) * 400 + n];
    __syncthreads();
    int wv = t >> 6, lane = t & 63;
    {
        int h = wv * 2 + (lane >> 5), mm0 = lane & 31;
        float fm = -1e30f;
        for (int m = mm0; m < 400; m += 32) fm = fmaxf(fm, f2l[h][m]);
#pragma unroll
        for (int s = 16; s >= 1; s >>= 1) fm = fmaxf(fm, __shfl_xor(fm, s, 64));
        if (mm0 == 0) fmax2[h] = fm;
    }
    __syncthreads();
    int g = t & 7, kq = (t >> 3) & 7;
    for (int hh = 0; hh < 2; ++hh) {
        int h = wv * 2 + hh;
        int bh = b * 8 + h;
        float f1n = f1l[h];
        float rm = leaky(f1n + fmax2[h]);
        float a0[4] = {0.f, 0.f, 0.f, 0.f};
        float ps = 0.f;
        const float4* WhG = (const float4*)(WhI + bh * 12800);
        for (int m = g; m < 400; m += 8) {
            float4 w4 = WhG[m * 8 + kq];
            float p = __expf(leaky(f1n + f2l[h][m]) - rm);
            ps += p;
            a0[0] += p * w4.x; a0[1] += p * w4.y; a0[2] += p * w4.z; a0[3] += p * w4.w;
        }
#pragma unroll
        for (int s = 4; s >= 1; s >>= 1) {
            ps += __shfl_xor(ps, s, 64);
#pragma unroll
            for (int c = 0; c < 4; ++c) a0[c] += __shfl_xor(a0[c], s, 64);
        }
        if (g == 0) {
            float4 o;
            float* ov = &o.x;
#pragma unroll
            for (int c = 0; c < 4; ++c) {
                float v = a0[c] / ps;
                ov[c] = v > 0.f ? v : (__expf(v) - 1.f);
            }
            *(float4*)&xout[(b * 400 + n) * 256 + h * 32 + kq * 4] = o;
        }
    }
}

// ---------- S5: out[r][v] = sum_d x[b,250+dn,d]*Wb[d][v] + b[v]
__global__ __launch_bounds__(256) void k_out(const float* x, const unsigned short* Wb,
                                             const float* bias, float* out) {
    int vt = blockIdx.x, rg = blockIdx.y, t = threadIdx.x;  // grid (10,50)
    __shared__ float xr[6][256];
    int r0 = rg * 6;
    int b = r0 / 150, n0 = 250 + (r0 % 150);
    for (int i = t; i < 1536; i += 256) {
        int rr = i >> 8, dd = i & 255;
        xr[rr][dd] = x[(b * 400 + n0 + rr) * 256 + dd];
    }
    __syncthreads();
    int v = vt * 512 + t * 2;
    if (v >= 5000) return;
    float acc[6][2];
#pragma unroll
    for (int rr = 0; rr < 6; ++rr) { acc[rr][0] = 0.f; acc[rr][1] = 0.f; }
    const unsigned short* Wp = Wb + v;
#pragma unroll 8
    for (int dd = 0; dd < 256; ++dd) {
        unsigned int wu = *reinterpret_cast<const unsigned int*>(Wp + dd * 5000);
        float w0 = bf2f_raw(wu & 0xFFFFu);
        float w1 = bf2f_raw(wu >> 16);
#pragma unroll
        for (int rr = 0; rr < 6; ++rr) {
            float xv = xr[rr][dd];
            acc[rr][0] += xv * w0;
            acc[rr][1] += xv * w1;
        }
    }
    float b0 = bias[v], b1 = bias[v + 1];
#pragma unroll
    for (int rr = 0; rr < 6; ++rr) {
        out[(r0 + rr) * 5000 + v]     = acc[rr][0] + b0;
        out[(r0 + rr) * 5000 + v + 1] = acc[rr][1] + b1;
    }
}

extern "C" void kernel_launch(void* const* d_in, const int* in_sizes, int n_in,
                              void* d_out, int out_size, void* d_ws, size_t ws_size,
                              hipStream_t stream) {
    const int*   enc   = (const int*)d_in[0];
    const int*   dec   = (const int*)d_in[1];
    const float* emb   = (const float*)d_in[3];
    const float* convw = (const float*)d_in[4];
    const float* convb = (const float*)d_in[5];
    const float* hstW  = (const float*)d_in[6];
    const float* hstb  = (const float*)d_in[7];
    const float* attW  = (const float*)d_in[15];
    const float* a1    = (const float*)d_in[16];
    const float* a2    = (const float*)d_in[17];
    const float* outW  = (const float*)d_in[18];
    const float* outb  = (const float*)d_in[19];
    float* out = (float*)d_out;

    char* ws = (char*)d_ws;
    float* T    = (float*)ws; ws += 5 * 128 * 128 * 4;
    float* WhA  = (float*)ws; ws += 16 * 400 * 32 * 4;
    float* WhB  = (float*)ws; ws += 16 * 400 * 32 * 4;
    float* f1A  = (float*)ws; ws += 16 * 400 * 4;
    float* f2A  = (float*)ws; ws += 16 * 400 * 4;
    float* f1B  = (float*)ws; ws += 16 * 400 * 4;
    float* f2B  = (float*)ws; ws += 16 * 400 * 4;
    float* x2   = (float*)ws; ws += 800 * 256 * 4;
    unsigned short* Wb = (unsigned short*)ws; ws += 256 * 5000 * 2;

    k_prep<<<2628, 256, 0, stream>>>(emb, convw, T, outW, Wb);
    k_convwh<<<400, 256, 0, stream>>>(enc, dec, convb, T, hstW, hstb, attW,
                                      a1, a2, WhA, f1A, f2A);
    k_attnwh<<<400, 256, 0, stream>>>(WhA, f1A, f2A, attW, a1, a2,
                                      WhB, f1B, f2B);
    k_attn2<<<300, 256, 0, stream>>>(WhB, f1B, f2B, x2);
    k_out<<<dim3(10, 50), 256, 0, stream>>>(x2, Wb, outb, out);
}

// Round 13
// 95.492 us; speedup vs baseline: 4.3609x; 1.4330x over previous
//
#include <hip/hip_runtime.h>
#include <hip/hip_bf16.h>
#include <math.h>

// Shapes: B=2, Le=250, Ld=150, N=400, Wl=16, Vin=128, E=64, F=128, K=5
//         H=8, hid=32, d=256, Vout=5000
// Inputs fp32, output fp32 (verified round 4). fixed_graph/dg_* dead:
// adj=clip(sigmoid+fixed,0,1) strictly positive => unmasked softmax.
// Round-12 lesson: fusing all 8 heads into 2-row blocks (k_attnwh/k_attn2)
// made PV 100 serial L2 loads/thread at 1.25 blocks/CU -> 48.7us + ~40us
// latency-bound. Reverted to the round-9 attention decomposition (one bh x
// 8 rows per block, 12.5-iter coalesced PV, ~3 blocks/CU) while keeping
// round-12's convwh fusion and decoder-only attn2:
//   S1 prep: conv table T + out_W->bf16
//   S2 conv+hst+Wh1 fused (x in LDS only)
//   S3 attn1 (50,16) -> x1 global
//   S4 wh2 (400 blocks) -> Wh2/f1B/f2B
//   S5 attn2 (19,16) decoder rows only (clamped tail; duplicate writes are
//      identical-value, benign) -> x2
//   S6 out

__device__ __forceinline__ float bf2f_raw(unsigned int u) {
    union { unsigned int i; float f; } cv; cv.i = u << 16; return cv.f;
}
__device__ __forceinline__ unsigned short f2bf(float f) {
    __hip_bfloat16 h = __float2bfloat16(f);
    return *reinterpret_cast<unsigned short*>(&h);
}

// ---------- S1: conv table T[k5][v][f] (blocks 0..127) + out_W->bf16 (rest)
__global__ __launch_bounds__(256) void k_prep(const float* emb, const float* convw,
                                              float* T, const float* W,
                                              unsigned short* Wb) {
    int bid = blockIdx.x, t = threadIdx.x;
    if (bid < 128) {
        int v = bid;
        __shared__ float er[64];
        if (t < 64) er[t] = emb[v * 64 + t];
        __syncthreads();
        if (t < 128) {
            float acc[5] = {0.f, 0.f, 0.f, 0.f, 0.f};
            const float* w = convw + t * 320;          // convw[f][e][k5]
            for (int e = 0; e < 64; ++e) {
                float xe = er[e];
#pragma unroll
                for (int k = 0; k < 5; ++k) acc[k] += xe * w[e * 5 + k];
            }
#pragma unroll
            for (int k = 0; k < 5; ++k) T[(k * 128 + v) * 128 + t] = acc[k];
        }
    } else {
        int i0 = (bid - 128) * 512 + t * 2;            // 2500 blocks * 512
        if (i0 < 256 * 5000) {
            float2 w2 = *reinterpret_cast<const float2*>(W + i0);
            unsigned int u = ((unsigned int)f2bf(w2.y) << 16) | f2bf(w2.x);
            *reinterpret_cast<unsigned int*>(Wb + i0) = u;
        }
    }
}

// ---------- S2: char conv + bias + relu + maxpool + hst + Wh1 + f1/f2.
__global__ __launch_bounds__(256) void k_convwh(const int* enc, const int* dec,
                                                const float* convb, const float* T,
                                                const float* hstW, const float* hstb,
                                                const float* attW,
                                                const float* a1g, const float* a2g,
                                                float* Wh, float* f1, float* f2) {
    int w0 = blockIdx.x * 2, t = threadIdx.x;          // grid 400
    __shared__ int ids[2][16];
    __shared__ float xcl[2][128];
    __shared__ float x0[2][256];
    if (t < 32) {
        int r = t >> 4, c = t & 15;
        int w = w0 + r, b = w / 400, n = w % 400;
        ids[r][c] = (n < 250) ? enc[(b * 250 + n) * 16 + c]
                              : dec[(b * 150 + (n - 250)) * 16 + c];
    }
    __syncthreads();
    {
        int r = t >> 7, f = t & 127;                   // conv: all 256 active
        float best = -1e30f;
        for (int p = 0; p < 16; ++p) {
            float s = 0.f;
#pragma unroll
            for (int k = 0; k < 5; ++k) {
                int q = p + k - 2;
                if (q >= 0 && q < 16) s += T[(k * 128 + ids[r][q]) * 128 + f];
            }
            best = fmaxf(best, s);
        }
        xcl[r][f] = fmaxf(best + convb[f], 0.f);
    }
    __syncthreads();
    {
        float acc0 = hstb[t], acc1 = acc0;             // hst: 2 rows share loads
        for (int c = 0; c < 128; ++c) {
            float wv = hstW[c * 256 + t];
            acc0 += xcl[0][c] * wv;
            acc1 += xcl[1][c] * wv;
        }
        x0[0][t] = acc0;
        x0[1][t] = acc1;
    }
    __syncthreads();
    int h = t >> 5, k = t & 31;                        // Wh1: thread (h,k)
    float acc0 = 0.f, acc1 = 0.f;
    const float* Wp = attW + h * 8192 + k;
#pragma unroll 8
    for (int d = 0; d < 256; ++d) {
        float wv = Wp[d * 32];
        acc0 += x0[0][d] * wv;
        acc1 += x0[1][d] * wv;
    }
    float a1v = a1g[t], a2v = a2g[t];
    int b = w0 / 400;
    int bh = b * 8 + h;
    float accs[2] = {acc0, acc1};
#pragma unroll
    for (int rw = 0; rw < 2; ++rw) {
        int n = (w0 + rw) % 400;
        Wh[(bh * 400 + n) * 32 + k] = accs[rw];
        float v1 = accs[rw] * a1v, v2 = accs[rw] * a2v;
#pragma unroll
        for (int mm = 16; mm >= 1; mm >>= 1) {
            v1 += __shfl_xor(v1, mm, 64);
            v2 += __shfl_xor(v2, mm, 64);
        }
        if (k == 0) { f1[bh * 400 + n] = v1; f2[bh * 400 + n] = v2; }
    }
}

// ---------- S4: Wh2 + fused f1/f2 from global x. 2 rows/block.
__global__ __launch_bounds__(256) void k_wh(const float* x, const float* attW,
                                            const float* a1g, const float* a2g,
                                            float* Wh, float* f1, float* f2) {
    int blk = blockIdx.x, t = threadIdx.x;             // grid 400
    int w0 = blk * 2;
    int h = t >> 5, k = t & 31;
    __shared__ float xr[2][256];
    for (int i = t; i < 512; i += 256) xr[i >> 8][i & 255] = x[w0 * 256 + i];
    __syncthreads();
    float acc0 = 0.f, acc1 = 0.f;
    const float* Wp = attW + h * 8192 + k;
#pragma unroll 8
    for (int d = 0; d < 256; ++d) {
        float wv = Wp[d * 32];
        acc0 += xr[0][d] * wv;
        acc1 += xr[1][d] * wv;
    }
    float a1v = a1g[t], a2v = a2g[t];
    int b = w0 / 400;
    int bh = b * 8 + h;
    float accs[2] = {acc0, acc1};
#pragma unroll
    for (int rw = 0; rw < 2; ++rw) {
        int n = (w0 + rw) % 400;
        Wh[(bh * 400 + n) * 32 + k] = accs[rw];
        float v1 = accs[rw] * a1v, v2 = accs[rw] * a2v;
#pragma unroll
        for (int mm = 16; mm >= 1; mm >>= 1) {
            v1 += __shfl_xor(v1, mm, 64);
            v2 += __shfl_xor(v2, mm, 64);
        }
        if (k == 0) { f1[bh * 400 + n] = v1; f2[bh * 400 + n] = v2; }
    }
}

// ---------- S3/S5: softmax + PV + elu. One bh x 8 rows per block (round-9
// form). n_base parameterizes full pass (0) vs decoder-only (250, clamped).
__global__ __launch_bounds__(256) void k_attn(const float* Wh, const float* f1g,
                                              const float* f2g, float* xout,
                                              int n_base) {
    int tile = blockIdx.x, bh = blockIdx.y;
    int b = bh >> 3, h = bh & 7;
    int t = threadIdx.x;
    int n0 = n_base + tile * 8;
    __shared__ float f2l[400];
    __shared__ float4 plT[400];                    // p transposed: [m][4 rows]
    __shared__ float f1l[8];
    __shared__ float red[4][8][4][4];              // [wave][kq][rw][c]
    __shared__ float sred[2][4][4];
    __shared__ float wmax[4];

    float fm = -1e30f;
    for (int m = t; m < 400; m += 256) {
        float v = f2g[bh * 400 + m];
        f2l[m] = v;
        fm = fmaxf(fm, v);
    }
    if (t < 8) {
        int n = n0 + t; if (n > 399) n = 399;
        f1l[t] = f1g[bh * 400 + n];
    }
#pragma unroll
    for (int mm = 32; mm >= 1; mm >>= 1) fm = fmaxf(fm, __shfl_xor(fm, mm, 64));
    if ((t & 63) == 0) wmax[t >> 6] = fm;
    __syncthreads();
    float fmax2 = fmaxf(fmaxf(wmax[0], wmax[1]), fmaxf(wmax[2], wmax[3]));

    int g = t & 7, kq = (t >> 3) & 7, wv = t >> 6;
    int gm = g + 8 * wv;                           // m-group 0..31
    const float4* WhG = (const float4*)(Wh + bh * 12800);
    for (int it = 0; it < 2; ++it) {
        // P1: all 4 rows' p at this thread's m -> plT[m]; denominator partials
        float f1a = f1l[it * 4 + 0], f1b = f1l[it * 4 + 1];
        float f1c = f1l[it * 4 + 2], f1d = f1l[it * 4 + 3];
        float rm0 = f1a + fmax2; rm0 = rm0 > 0.f ? rm0 : 0.2f * rm0;
        float rm1 = f1b + fmax2; rm1 = rm1 > 0.f ? rm1 : 0.2f * rm1;
        float rm2 = f1c + fmax2; rm2 = rm2 > 0.f ? rm2 : 0.2f * rm2;
        float rm3 = f1d + fmax2; rm3 = rm3 > 0.f ? rm3 : 0.2f * rm3;
        float ps0 = 0.f, ps1 = 0.f, ps2 = 0.f, ps3 = 0.f;
        for (int m = t; m < 400; m += 256) {
            float f2v = f2l[m];
            float e0 = f1a + f2v; e0 = e0 > 0.f ? e0 : 0.2f * e0;
            float e1 = f1b + f2v; e1 = e1 > 0.f ? e1 : 0.2f * e1;
            float e2 = f1c + f2v; e2 = e2 > 0.f ? e2 : 0.2f * e2;
            float e3 = f1d + f2v; e3 = e3 > 0.f ? e3 : 0.2f * e3;
            float4 pv;
            pv.x = __expf(e0 - rm0); ps0 += pv.x;
            pv.y = __expf(e1 - rm1); ps1 += pv.y;
            pv.z = __expf(e2 - rm2); ps2 += pv.z;
            pv.w = __expf(e3 - rm3); ps3 += pv.w;
            plT[m] = pv;
        }
#pragma unroll
        for (int mm = 32; mm >= 1; mm >>= 1) {
            ps0 += __shfl_xor(ps0, mm, 64);
            ps1 += __shfl_xor(ps1, mm, 64);
            ps2 += __shfl_xor(ps2, mm, 64);
            ps3 += __shfl_xor(ps3, mm, 64);
        }
        if ((t & 63) == 0) {
            int wq = t >> 6;
            sred[it & 1][0][wq] = ps0; sred[it & 1][1][wq] = ps1;
            sred[it & 1][2][wq] = ps2; sred[it & 1][3][wq] = ps3;
        }
        __syncthreads();
        // P2: 4 rows x 4 cols; 1 global b128 (Wh, L2) + 1 LDS b128 (plT) per m
        float a[4][4];
#pragma unroll
        for (int rr = 0; rr < 4; ++rr)
#pragma unroll
            for (int c = 0; c < 4; ++c) a[rr][c] = 0.f;
#pragma unroll 4
        for (int m = gm; m < 400; m += 32) {
            float4 w4 = WhG[m * 8 + kq];
            float4 p4 = plT[m];
            a[0][0] += p4.x * w4.x; a[0][1] += p4.x * w4.y; a[0][2] += p4.x * w4.z; a[0][3] += p4.x * w4.w;
            a[1][0] += p4.y * w4.x; a[1][1] += p4.y * w4.y; a[1][2] += p4.y * w4.z; a[1][3] += p4.y * w4.w;
            a[2][0] += p4.z * w4.x; a[2][1] += p4.z * w4.y; a[2][2] += p4.z * w4.z; a[2][3] += p4.z * w4.w;
            a[3][0] += p4.w * w4.x; a[3][1] += p4.w * w4.y; a[3][2] += p4.w * w4.z; a[3][3] += p4.w * w4.w;
        }
#pragma unroll
        for (int rr = 0; rr < 4; ++rr)
#pragma unroll
            for (int c = 0; c < 4; ++c) {
                float v = a[rr][c];
                v += __shfl_xor(v, 1, 64);             // DPP, off the LDS pipe
                v += __shfl_xor(v, 2, 64);
                v += __shfl_xor(v, 4, 64);
                a[rr][c] = v;
            }
        if (g == 0) {
#pragma unroll
            for (int rr = 0; rr < 4; ++rr)
#pragma unroll
                for (int c = 0; c < 4; ++c) red[wv][kq][rr][c] = a[rr][c];
        }
        __syncthreads();
        // P3: combine 4 wave-partials, normalize, elu, store
        if (t < 128) {
            int rw3 = t >> 5, kk = t & 31;
            int q3 = kk >> 2, c3 = kk & 3;
            float s = sred[it & 1][rw3][0] + sred[it & 1][rw3][1]
                    + sred[it & 1][rw3][2] + sred[it & 1][rw3][3];
            float o = (red[0][q3][rw3][c3] + red[1][q3][rw3][c3]
                     + red[2][q3][rw3][c3] + red[3][q3][rw3][c3]) / s;
            o = o > 0.f ? o : (__expf(o) - 1.f);       // elu
            int n = n0 + it * 4 + rw3;
            if (n > 399) n = 399;                      // clamped dup: same value
            xout[(b * 400 + n) * 256 + h * 32 + kk] = o;
        }
        __syncthreads();
    }
}

// ---------- S6: out[r][v] = sum_d x[b,250+dn,d]*Wb[d][v] + b[v]
__global__ __launch_bounds__(256) void k_out(const float* x, const unsigned short* Wb,
                                             const float* bias, float* out) {
    int vt = blockIdx.x, rg = blockIdx.y, t = threadIdx.x;  // grid (10,50)
    __shared__ float xr[6][256];
    int r0 = rg * 6;
    int b = r0 / 150, n0 = 250 + (r0 % 150);
    for (int i = t; i < 1536; i += 256) {
        int rr = i >> 8, dd = i & 255;
        xr[rr][dd] = x[(b * 400 + n0 + rr) * 256 + dd];
    }
    __syncthreads();
    int v = vt * 512 + t * 2;
    if (v >= 5000) return;
    float acc[6][2];
#pragma unroll
    for (int rr = 0; rr < 6; ++rr) { acc[rr][0] = 0.f; acc[rr][1] = 0.f; }
    const unsigned short* Wp = Wb + v;
#pragma unroll 8
    for (int dd = 0; dd < 256; ++dd) {
        unsigned int wu = *reinterpret_cast<const unsigned int*>(Wp + dd * 5000);
        float w0 = bf2f_raw(wu & 0xFFFFu);
        float w1 = bf2f_raw(wu >> 16);
#pragma unroll
        for (int rr = 0; rr < 6; ++rr) {
            float xv = xr[rr][dd];
            acc[rr][0] += xv * w0;
            acc[rr][1] += xv * w1;
        }
    }
    float b0 = bias[v], b1 = bias[v + 1];
#pragma unroll
    for (int rr = 0; rr < 6; ++rr) {
        out[(r0 + rr) * 5000 + v]     = acc[rr][0] + b0;
        out[(r0 + rr) * 5000 + v + 1] = acc[rr][1] + b1;
    }
}

extern "C" void kernel_launch(void* const* d_in, const int* in_sizes, int n_in,
                              void* d_out, int out_size, void* d_ws, size_t ws_size,
                              hipStream_t stream) {
    const int*   enc   = (const int*)d_in[0];
    const int*   dec   = (const int*)d_in[1];
    const float* emb   = (const float*)d_in[3];
    const float* convw = (const float*)d_in[4];
    const float* convb = (const float*)d_in[5];
    const float* hstW  = (const float*)d_in[6];
    const float* hstb  = (const float*)d_in[7];
    const float* attW  = (const float*)d_in[15];
    const float* a1    = (const float*)d_in[16];
    const float* a2    = (const float*)d_in[17];
    const float* outW  = (const float*)d_in[18];
    const float* outb  = (const float*)d_in[19];
    float* out = (float*)d_out;

    char* ws = (char*)d_ws;
    float* T    = (float*)ws; ws += 5 * 128 * 128 * 4;
    float* WhA  = (float*)ws; ws += 16 * 400 * 32 * 4;
    float* WhB  = (float*)ws; ws += 16 * 400 * 32 * 4;
    float* f1A  = (float*)ws; ws += 16 * 400 * 4;
    float* f2A  = (float*)ws; ws += 16 * 400 * 4;
    float* f1B  = (float*)ws; ws += 16 * 400 * 4;
    float* f2B  = (float*)ws; ws += 16 * 400 * 4;
    float* x1   = (float*)ws; ws += 800 * 256 * 4;
    float* x2   = (float*)ws; ws += 800 * 256 * 4;
    unsigned short* Wb = (unsigned short*)ws; ws += 256 * 5000 * 2;

    k_prep<<<2628, 256, 0, stream>>>(emb, convw, T, outW, Wb);
    k_convwh<<<400, 256, 0, stream>>>(enc, dec, convb, T, hstW, hstb, attW,
                                      a1, a2, WhA, f1A, f2A);
    k_attn<<<dim3(50, 16), 256, 0, stream>>>(WhA, f1A, f2A, x1, 0);
    k_wh<<<400, 256, 0, stream>>>(x1, attW, a1, a2, WhB, f1B, f2B);
    k_attn<<<dim3(19, 16), 256, 0, stream>>>(WhB, f1B, f2B, x2, 250);
    k_out<<<dim3(10, 50), 256, 0, stream>>>(x2, Wb, outb, out);
}